// Round 7
// baseline (32.990 us; speedup 1.0000x reference)
//
#include <hip/hip_runtime.h>
#include <hip/hip_bf16.h>
#include <math.h>

// Cylindrical pooling: for each box, select first S in-radius points (ascending
// index), append box velocity, zero remaining slots.
//
// Exact f32 semantics: reference computes dis = sqrt_rn(dx*dx + dy*dy) (no FMA
// contraction) and tests dis <= r. sqrt_rn is monotone, so dis <= r  <=>
// d2 <= T where T = max{x : sqrt_rn(x) <= r}, found by a 64-lane window probe
// (bit-pattern order == float order for non-negative floats).
//
// Two-kernel plan (R6 showed 3-dispatch adaptive ~= launch/gap bound; full
// counting is cheap if the inner loop is tight):
//  K1: point-major full count. Each block: 1024-pt tile x 32 boxes. Box params
//      staged in LDS, pulled 8-at-a-time into registers; packed-f32 (v_pk_*)
//      math at 2 pairs/instr; ballots -> per-group counts (int4 stores).
//  K2: per-box scan of group counts + worklist + ordered emission.
// fp contract(off) everywhere: d2 must be mul,mul,add with no FMA fusion.

#define MCHUNK 32   // boxes per K1 block

typedef float v2f __attribute__((ext_vector_type(2)));

__device__ __forceinline__ float box_radius(const float* __restrict__ b) {
    float hx = __fmul_rn(b[3], 0.5f);
    float hy = __fmul_rn(b[4], 0.5f);
    float nrm = __fsqrt_rn(__fadd_rn(__fmul_rn(hx, hx), __fmul_rn(hy, hy)));
    return __fmul_rn(nrm, 1.1f);   // GAMMA
}

// largest x with __fsqrt_rn(x) <= r, searched in a 64-ulp window around r*r.
// All 64 lanes of the wave participate (call under wave-uniform control flow).
__device__ __forceinline__ float probe_T(float r, int lane) {
    int xb = __float_as_int(__fmul_rn(r, r));      // r >= 0 so xb >= 0
    int yb = xb + lane - 32; if (yb < 0) yb = 0;
    bool ok = __fsqrt_rn(__int_as_float(yb)) <= r; // monotone in yb
    unsigned long long mask = __ballot(ok);        // lane 0 ok (sqrt(>=0 clamp) <= r)
    int hi = 63 - __clzll(mask);
    int tb = xb + hi - 32; if (tb < 0) tb = 0;
    return __int_as_float(tb);
}

__device__ __forceinline__ bool pt_in(float bx, float by, float T,
                                      float px, float py) {
    float dx = __fsub_rn(bx, px);
    float dy = __fsub_rn(by, py);
    float d2 = __fadd_rn(__fmul_rn(dx, dx), __fmul_rn(dy, dy));
    return d2 <= T;
}

// ---------------- K1: full per-(box, 64-pt-group) counts ----------------
// Grid: ntile x mcols blocks, 256 threads. Wave w holds 4 groups (256 pts);
// block covers 16 groups x MCHUNK boxes.
__global__ __launch_bounds__(256) void count_kernel(
    const float* __restrict__ pts, const float* __restrict__ boxes,
    int* __restrict__ counts, int N, int M, int ngrp, int ntile) {
#pragma clang fp contract(off)
    __shared__ float4 s_prm[MCHUNK];
    int tid = threadIdx.x;
    int lane = tid & 63;
    int wid = tid >> 6;

    int tile = blockIdx.x % ntile;
    int m0 = (blockIdx.x / ntile) * MCHUNK;

    // prologue: wave w computes params for boxes m0 + w*8 .. w*8+7
    #pragma unroll
    for (int jj = 0; jj < 8; ++jj) {
        int j = wid * 8 + jj;
        int m = m0 + j;
        float bx = 0.f, by = 0.f, T = -1.0f;   // T=-1: d2<=T never true
        if (m < M) {
            const float* b = boxes + (size_t)m * 9;
            bx = b[0]; by = b[1];
            T = probe_T(box_radius(b), lane);
        }
        if (lane == 0) s_prm[j] = make_float4(bx, by, T, 0.f);
    }
    __syncthreads();

    int pbase = tile * 1024 + wid * 256;
    int g0 = pbase >> 6;
    if (g0 >= ngrp) return;                    // wave-uniform; no syncs below
    bool vec4 = ((ngrp & 3) == 0) && (g0 + 4 <= ngrp);

    // 4 groups of 64 points, packed two-per-register for v_pk_* math
    v2f pxA, pyA, pxB, pyB;
    {
        int p0 = pbase + 0 * 64 + lane, p1 = pbase + 1 * 64 + lane;
        int p2 = pbase + 2 * 64 + lane, p3 = pbase + 3 * 64 + lane;
        pxA.x = p0 < N ? pts[(size_t)p0 * 5 + 0] : 3.0e38f;
        pyA.x = p0 < N ? pts[(size_t)p0 * 5 + 1] : 3.0e38f;
        pxA.y = p1 < N ? pts[(size_t)p1 * 5 + 0] : 3.0e38f;
        pyA.y = p1 < N ? pts[(size_t)p1 * 5 + 1] : 3.0e38f;
        pxB.x = p2 < N ? pts[(size_t)p2 * 5 + 0] : 3.0e38f;
        pyB.x = p2 < N ? pts[(size_t)p2 * 5 + 1] : 3.0e38f;
        pxB.y = p3 < N ? pts[(size_t)p3 * 5 + 0] : 3.0e38f;
        pyB.y = p3 < N ? pts[(size_t)p3 * 5 + 1] : 3.0e38f;
    }

    #pragma unroll 1
    for (int oct = 0; oct < MCHUNK / 8; ++oct) {
        float4 prm[8];
        #pragma unroll
        for (int j = 0; j < 8; ++j) prm[j] = s_prm[oct * 8 + j];
        #pragma unroll
        for (int j = 0; j < 8; ++j) {
            v2f bxv = {prm[j].x, prm[j].x};
            v2f byv = {prm[j].y, prm[j].y};
            float T = prm[j].z;
            v2f dxA = bxv - pxA, dyA = byv - pyA;
            v2f dxB = bxv - pxB, dyB = byv - pyB;
            v2f d2A = dxA * dxA + dyA * dyA;   // contract(off): mul,mul,add
            v2f d2B = dxB * dxB + dyB * dyB;
            int c0 = __popcll(__ballot(d2A.x <= T));
            int c1 = __popcll(__ballot(d2A.y <= T));
            int c2 = __popcll(__ballot(d2B.x <= T));
            int c3 = __popcll(__ballot(d2B.y <= T));
            int m = m0 + oct * 8 + j;
            if (lane == 0 && m < M) {
                int* dst = counts + (size_t)m * ngrp + g0;
                if (vec4) {
                    *reinterpret_cast<int4*>(dst) = make_int4(c0, c1, c2, c3);
                } else {
                    dst[0] = c0;
                    if (g0 + 1 < ngrp) dst[1] = c1;
                    if (g0 + 2 < ngrp) dst[2] = c2;
                    if (g0 + 3 < ngrp) dst[3] = c3;
                }
            }
        }
    }
}

// ---------------- K2: per-box scan + worklist + ordered emission ----------
// Grid: M blocks x 1024 threads.
__global__ __launch_bounds__(1024) void emit_kernel(
    const float* __restrict__ pts, const float* __restrict__ boxes,
    const int* __restrict__ counts, float* __restrict__ out,
    int N, int M, int S, int ngrp) {
#pragma clang fp contract(off)
    extern __shared__ int s_work[];        // S + 64 entries
    __shared__ int s_wsum[16];
    __shared__ int s_nwork;
    __shared__ float s_prm[3];

    int m = blockIdx.x;
    int tid = threadIdx.x;
    int lane = tid & 63;
    int wid = tid >> 6;

    if (tid == 0) s_nwork = 0;
    if (wid == 0) {                         // wave 0: box params via probe
        const float* b = boxes + (size_t)m * 9;
        float bx = b[0], by = b[1];
        float T = probe_T(box_radius(b), lane);
        if (lane == 0) { s_prm[0] = bx; s_prm[1] = by; s_prm[2] = T; }
    }
    float vx = boxes[(size_t)m * 9 + 7];
    float vy = boxes[(size_t)m * 9 + 8];

    const int* my_counts = counts + (size_t)m * ngrp;
    int gpt = (ngrp + 1023) >> 10;          // <= 8 (launcher guard)
    int g0 = tid * gpt;

    int c[8];
    int tsum = 0;
    if (gpt == 4 && ((ngrp & 3) == 0) && g0 + 3 < ngrp) {
        int4 v4 = *reinterpret_cast<const int4*>(my_counts + g0);
        c[0] = v4.x; c[1] = v4.y; c[2] = v4.z; c[3] = v4.w;
        tsum = c[0] + c[1] + c[2] + c[3];
    } else {
        #pragma unroll
        for (int i = 0; i < 8; ++i) {
            int g = g0 + i;
            c[i] = (i < gpt && g < ngrp) ? my_counts[g] : 0;
            tsum += c[i];
        }
    }

    // wave-inclusive scan of tsum
    int v = tsum;
    #pragma unroll
    for (int d = 1; d < 64; d <<= 1) {
        int u = __shfl_up(v, d, 64);
        if (lane >= d) v += u;
    }
    if (lane == 63) s_wsum[wid] = v;
    __syncthreads();                        // covers s_prm, s_wsum, s_nwork

    float bx = s_prm[0], by = s_prm[1], T = s_prm[2];

    int woff = 0, total = 0;
    #pragma unroll
    for (int w = 0; w < 16; ++w) {
        int s = s_wsum[w];
        total += s;
        if (w < wid) woff += s;
    }
    int base = woff + (v - tsum);           // exclusive prefix of thread's groups

    for (int i = 0; i < gpt; ++i) {
        int g = g0 + i;
        if (g < ngrp) {
            int cnt = c[i];
            if (cnt > 0 && base < S) {
                int slot = atomicAdd(&s_nwork, 1);
                s_work[slot] = (base << 16) | g;
            }
            base += cnt;
        }
    }
    __syncthreads();
    int nwork = s_nwork;

    // emission: one wave per worklist entry
    for (int i = wid; i < nwork; i += 16) {
        int e = s_work[i];
        int g = e & 0xffff;
        int gbase = e >> 16;
        int p = g * 64 + lane;
        bool in = false;
        float px = 0.f, py = 0.f;
        if (p < N) {
            px = pts[(size_t)p * 5 + 0];
            py = pts[(size_t)p * 5 + 1];
            in = pt_in(bx, by, T, px, py);
        }
        unsigned long long bal = __ballot(in);
        int rank = __popcll(bal & ((1ull << lane) - 1ull));
        int pos = gbase + rank;
        if (in && pos < S) {
            float* o = out + ((size_t)m * S + pos) * 7;
            const float* pp = pts + (size_t)p * 5;
            o[0] = px;    o[1] = py;    o[2] = pp[2];
            o[3] = pp[3]; o[4] = pp[4];
            o[5] = vx;    o[6] = vy;
        }
    }

    // zero-fill tail slots [min(total,S), S)
    int cnt = total < S ? total : S;
    size_t outbase = (size_t)m * S * 7;
    for (int i = cnt * 7 + tid; i < S * 7; i += 1024) out[outbase + i] = 0.0f;
}

// ---------------- Fallback: serialized scan (guards failed) ----------------
__device__ float sqrt_le_threshold(float r) {
    float x = __fmul_rn(r, r);
    #pragma unroll 1
    for (int i = 0; i < 16; ++i) {
        float nx = nextafterf(x, INFINITY);
        if (__fsqrt_rn(nx) <= r) x = nx; else break;
    }
    #pragma unroll 1
    for (int i = 0; i < 16; ++i) {
        if (__fsqrt_rn(x) <= r) break;
        x = nextafterf(x, -INFINITY);
    }
    return x;
}

__global__ __launch_bounds__(256) void simple_kernel(
    const float* __restrict__ pts, const float* __restrict__ boxes,
    float* __restrict__ out, int N, int M, int S) {
    __shared__ int s_wc[4];
    int m = blockIdx.x;
    int tid = threadIdx.x;
    int lane = tid & 63;
    int wid = tid >> 6;

    const float* b = boxes + (size_t)m * 9;
    float bx = b[0], by = b[1];
    float T = sqrt_le_threshold(box_radius(b));
    float vx = b[7], vy = b[8];

    int base = 0;
    for (int start = 0; start < N && base < S; start += 256) {
        int p = start + tid;
        bool in = false;
        if (p < N) {
            float px = pts[(size_t)p * 5 + 0];
            float py = pts[(size_t)p * 5 + 1];
            in = pt_in(bx, by, T, px, py);
        }
        unsigned long long bal = __ballot(in);
        if (lane == 0) s_wc[wid] = __popcll(bal);
        __syncthreads();
        int off = 0;
        for (int w = 0; w < wid; ++w) off += s_wc[w];
        int pos = base + off + __popcll(bal & ((1ull << lane) - 1ull));
        if (in && pos < S) {
            float* o = out + ((size_t)m * S + pos) * 7;
            const float* pp = pts + (size_t)p * 5;
            o[0] = pp[0]; o[1] = pp[1]; o[2] = pp[2];
            o[3] = pp[3]; o[4] = pp[4];
            o[5] = vx;    o[6] = vy;
        }
        base += s_wc[0] + s_wc[1] + s_wc[2] + s_wc[3];
        __syncthreads();
    }

    int cnt = base < S ? base : S;
    size_t outbase = (size_t)m * S * 7;
    for (int i = cnt * 7 + tid; i < S * 7; i += 256) out[outbase + i] = 0.0f;
}

extern "C" void kernel_launch(void* const* d_in, const int* in_sizes, int n_in,
                              void* d_out, int out_size, void* d_ws, size_t ws_size,
                              hipStream_t stream) {
    const float* pts = (const float*)d_in[0];
    const float* boxes = (const float*)d_in[1];
    float* out = (float*)d_out;

    int N = in_sizes[0] / 5;
    int M = in_sizes[1] / 9;
    int S = out_size / (M * 7);
    int ngrp = (N + 63) / 64;

    size_t need = (size_t)M * ngrp * sizeof(int);

    if (ws_size >= need && S >= 1 && S < 32768 && ngrp <= 8192 && M <= 65535) {
        int* counts = (int*)d_ws;
        int ntile = (N + 1023) / 1024;
        int mcols = (M + MCHUNK - 1) / MCHUNK;
        count_kernel<<<ntile * mcols, 256, 0, stream>>>(
            pts, boxes, counts, N, M, ngrp, ntile);
        size_t lds = (size_t)(S + 64) * sizeof(int);
        emit_kernel<<<M, 1024, lds, stream>>>(pts, boxes, counts, out,
                                              N, M, S, ngrp);
    } else {
        simple_kernel<<<M, 256, 0, stream>>>(pts, boxes, out, N, M, S);
    }
}